// Round 10
// baseline (370.789 us; speedup 1.0000x reference)
//
#include <hip/hip_runtime.h>
#include <hip/hip_bf16.h>
#include <cstdint>

typedef __bf16 bf16_t;
typedef __bf16 bf16x8 __attribute__((ext_vector_type(8)));
typedef __bf16 bf16x4v __attribute__((ext_vector_type(4)));
typedef short s16x4 __attribute__((ext_vector_type(4)));
typedef float f32x4 __attribute__((ext_vector_type(4)));

#define B_ 2
#define L_ 2048
#define D_ 1024
#define H_ 16
#define DH_ 64
#define FF_ 4096
#define M_TOT (B_*L_)

// 0.125 (DH^-0.5) * log2(e): folded into Q at the QKV epilogue
#define CLOG2 0.18033688011112042f

// ---------------------------------------------------------------- utilities

__device__ __forceinline__ void gload_lds16(const void* g, void* l) {
    __builtin_amdgcn_global_load_lds((__attribute__((address_space(1))) void*)g,
                                     (__attribute__((address_space(3))) void*)l,
                                     16, 0, 0);
}

__device__ __forceinline__ float fast_exp2(float v) {
    return __builtin_amdgcn_exp2f(v);
}

// tanh-form GELU: 0.5x(1+tanh(0.79788456(x+0.044715x^3))), tanh via exp2+rcp.
__device__ __forceinline__ float gelu_fast(float x) {
    float x3 = x * x * x;
    float y  = fmaf(0.044715f, x3, x);
    float e  = fast_exp2(y * 2.3022213f);   // exp(2*0.79788456*y)
    float t  = fmaf(-2.0f, __builtin_amdgcn_rcpf(e + 1.0f), 1.0f);
    return 0.5f * x * (1.0f + t);
}

// ------------------------------------------------- weight transpose + cast
// 64x64 tiles, float4 reads, bf16x4 packed writes (512B/wave write segments;
// old 32x32 version wrote 64B segments -> ~2x the time on 72MB of traffic).
// W [K,N] fp32 row-major -> WT [N,K] bf16 row-major. tb(16,16).
__global__ void transpose_bf16_kernel(const float* __restrict__ W, bf16_t* __restrict__ WT,
                                      int K, int N) {
    __shared__ float t[64][65];
    int tx = threadIdx.x, ty = threadIdx.y;
    int n0 = blockIdx.x * 64, k0 = blockIdx.y * 64;
#pragma unroll
    for (int i = 0; i < 4; i++) {
        int r = ty * 4 + i;
        float4 v = *(const float4*)(W + (size_t)(k0 + r) * N + n0 + tx * 4);
        t[r][tx * 4 + 0] = v.x; t[r][tx * 4 + 1] = v.y;
        t[r][tx * 4 + 2] = v.z; t[r][tx * 4 + 3] = v.w;
    }
    __syncthreads();
#pragma unroll
    for (int i = 0; i < 4; i++) {
        int r = ty * 4 + i;
        bf16x4v pk;
#pragma unroll
        for (int j = 0; j < 4; j++) pk[j] = (bf16_t)t[tx * 4 + j][r];
        *(bf16x4v*)(WT + (size_t)(n0 + r) * K + k0 + tx * 4) = pk;
    }
}

// fused: 4x 1024x1024 weights in one launch (z selects source)
__global__ void transpose_qkvo_kernel(const float* __restrict__ Wq, const float* __restrict__ Wk,
                                      const float* __restrict__ Wv, const float* __restrict__ Wo,
                                      bf16_t* __restrict__ WqkvT, bf16_t* __restrict__ WoT) {
    int z = blockIdx.z;
    const float* W = (z == 0) ? Wq : (z == 1) ? Wk : (z == 2) ? Wv : Wo;
    bf16_t* dst = (z < 3) ? (WqkvT + (size_t)z * 1024 * 1024) : WoT;
    __shared__ float t[64][65];
    int tx = threadIdx.x, ty = threadIdx.y;
    int n0 = blockIdx.x * 64, k0 = blockIdx.y * 64;
#pragma unroll
    for (int i = 0; i < 4; i++) {
        int r = ty * 4 + i;
        float4 v = *(const float4*)(W + (size_t)(k0 + r) * D_ + n0 + tx * 4);
        t[r][tx * 4 + 0] = v.x; t[r][tx * 4 + 1] = v.y;
        t[r][tx * 4 + 2] = v.z; t[r][tx * 4 + 3] = v.w;
    }
    __syncthreads();
#pragma unroll
    for (int i = 0; i < 4; i++) {
        int r = ty * 4 + i;
        bf16x4v pk;
#pragma unroll
        for (int j = 0; j < 4; j++) pk[j] = (bf16_t)t[tx * 4 + j][r];
        *(bf16x4v*)(dst + (size_t)(n0 + r) * D_ + k0 + tx * 4) = pk;
    }
}

// ---------------------------------------------------------------- layernorm
__global__ __launch_bounds__(256) void ln_kernel(const float* __restrict__ x,
                                                 const float* __restrict__ pos,
                                                 const float* __restrict__ g,
                                                 const float* __restrict__ beta,
                                                 bf16_t* __restrict__ out) {
    int row = blockIdx.x, tid = threadIdx.x;
    const float* xr = x + (size_t)row * D_;
    float v[4];
    float s = 0.f, sq = 0.f;
#pragma unroll
    for (int i = 0; i < 4; i++) {
        float a = xr[tid + 256 * i];
        v[i] = a; s += a; sq += a * a;
    }
#pragma unroll
    for (int o = 32; o > 0; o >>= 1) { s += __shfl_xor(s, o); sq += __shfl_xor(sq, o); }
    __shared__ float red[8];
    int wid = tid >> 6;
    if ((tid & 63) == 0) { red[wid] = s; red[4 + wid] = sq; }
    __syncthreads();
    s  = red[0] + red[1] + red[2] + red[3];
    sq = red[4] + red[5] + red[6] + red[7];
    float mu  = s * (1.f / D_);
    float var = sq * (1.f / D_) - mu * mu;
    float rs  = rsqrtf(var + 1e-5f);
    int l = row & (L_ - 1);
#pragma unroll
    for (int i = 0; i < 4; i++) {
        int c = tid + 256 * i;
        float hv = (v[i] - mu) * rs * g[c] + beta[c];
        if (pos) hv += pos[(size_t)l * D_ + c];
        out[(size_t)row * D_ + c] = (bf16_t)hv;
    }
}

// ----------------- fused: x2 = x + bo + P0 + P1 ; mb = LN(x2)*g+beta (bf16)
__global__ __launch_bounds__(256) void ln_fuse_kernel(const float* __restrict__ x,
                                                      const float* __restrict__ bo,
                                                      const float* __restrict__ P0,
                                                      const float* __restrict__ P1,
                                                      const float* __restrict__ g,
                                                      const float* __restrict__ beta,
                                                      float* __restrict__ x2,
                                                      bf16_t* __restrict__ out) {
    int row = blockIdx.x, tid = threadIdx.x;
    size_t base = (size_t)row * D_;
    float v[4];
    float s = 0.f, sq = 0.f;
#pragma unroll
    for (int i = 0; i < 4; i++) {
        int c = tid + 256 * i;
        float a = x[base + c] + bo[c] + P0[base + c] + P1[base + c];
        v[i] = a; s += a; sq += a * a;
        x2[base + c] = a;
    }
#pragma unroll
    for (int o = 32; o > 0; o >>= 1) { s += __shfl_xor(s, o); sq += __shfl_xor(sq, o); }
    __shared__ float red[8];
    int wid = tid >> 6;
    if ((tid & 63) == 0) { red[wid] = s; red[4 + wid] = sq; }
    __syncthreads();
    s  = red[0] + red[1] + red[2] + red[3];
    sq = red[4] + red[5] + red[6] + red[7];
    float mu  = s * (1.f / D_);
    float var = sq * (1.f / D_) - mu * mu;
    float rs  = rsqrtf(var + 1e-5f);
#pragma unroll
    for (int i = 0; i < 4; i++) {
        int c = tid + 256 * i;
        out[base + c] = (bf16_t)((v[i] - mu) * rs * g[c] + beta[c]);
    }
}

// ------------- final: dout = x2 + bias + P0(in dout) + P1  (vectorized)
__global__ __launch_bounds__(256) void reduce_out_kernel(const float* __restrict__ x2,
                                                         const float* __restrict__ bias,
                                                         const float* __restrict__ P1,
                                                         float* __restrict__ dout) {
    int i = (blockIdx.x * 256 + threadIdx.x) * 4;
    float4 a  = *(const float4*)(x2 + i);
    float4 bv = *(const float4*)(bias + (i & (D_ - 1)));
    float4 p0 = *(const float4*)(dout + i);
    float4 p1 = *(const float4*)(P1 + i);
    a.x += bv.x + p0.x + p1.x;
    a.y += bv.y + p0.y + p1.y;
    a.z += bv.z + p0.z + p1.z;
    a.w += bv.w + p0.w + p1.w;
    *(float4*)(dout + i) = a;
}

// ------------------------------------- GEMM 128x128, BK=32, double-buffered
// XOR source-chunk swizzle on staging (lane-linear LDS dest); read-side
// swizzle (row>>1)&3 -> 2-way max (free), verified SQ_LDS_BANK_CONFLICT=0.
// EPI: 2 = +bias,GELU (bf16 out); 4 = fused QKV (q cols scaled by CLOG2;
//      cols<2048 -> qk stride 2048; cols>=2048 -> Vt transposed)
template <int EPI, typename OutT>
__global__ __launch_bounds__(256) void gemm_kernel(const bf16_t* __restrict__ A,
                                                   const bf16_t* __restrict__ BT,
                                                   OutT* __restrict__ C,
                                                   const float* __restrict__ bias,
                                                   bf16_t* __restrict__ Vt,
                                                   int M, int N, int K) {
    __shared__ __align__(16) bf16_t sA[2][128 * 32];
    __shared__ __align__(16) bf16_t sB[2][128 * 32];
    int tid = threadIdx.x;
    int lane = tid & 63, w = tid >> 6, wy = w >> 1, wx = w & 1;
    int qm = lane & 15, quad = lane >> 4;
    int row0 = blockIdx.x * 128, col0 = blockIdx.y * 128;
    f32x4 acc[4][4] = {};
    int sf[2], sra[2], scol[2];
#pragma unroll
    for (int c = 0; c < 2; c++) {
        int f = tid * 8 + c * 2048;
        sf[c] = f;
        sra[c] = f >> 5;
        int ch = (f >> 3) & 3;
        scol[c] = ((ch ^ ((sra[c] >> 1) & 3)) << 3);
    }
    int aoff[4], boff[4];
#pragma unroll
    for (int t = 0; t < 4; t++) {
        int Ra = wy * 64 + t * 16 + qm;
        int Rb = wx * 64 + t * 16 + qm;
        aoff[t] = Ra * 32 + ((quad ^ ((Ra >> 1) & 3)) << 3);
        boff[t] = Rb * 32 + ((quad ^ ((Rb >> 1) & 3)) << 3);
    }
    const bf16_t* Ab = A  + (size_t)row0 * K;
    const bf16_t* Bb = BT + (size_t)col0 * K;
#pragma unroll
    for (int c = 0; c < 2; c++) {
        gload_lds16(Ab + (size_t)sra[c] * K + scol[c], &sA[0][sf[c]]);
        gload_lds16(Bb + (size_t)sra[c] * K + scol[c], &sB[0][sf[c]]);
    }
    for (int k0 = 0; k0 < K; k0 += 32) {
        int cur = (k0 >> 5) & 1;
        __syncthreads();
        int kn = k0 + 32;
        if (kn < K) {
#pragma unroll
            for (int c = 0; c < 2; c++) {
                gload_lds16(Ab + (size_t)sra[c] * K + kn + scol[c], &sA[cur ^ 1][sf[c]]);
                gload_lds16(Bb + (size_t)sra[c] * K + kn + scol[c], &sB[cur ^ 1][sf[c]]);
            }
        }
        bf16x8 af[4], bfr[4];
#pragma unroll
        for (int mt = 0; mt < 4; mt++) af[mt] = *(const bf16x8*)&sA[cur][aoff[mt]];
#pragma unroll
        for (int nt = 0; nt < 4; nt++) bfr[nt] = *(const bf16x8*)&sB[cur][boff[nt]];
#pragma unroll
        for (int mt = 0; mt < 4; mt++)
#pragma unroll
            for (int nt = 0; nt < 4; nt++)
                acc[mt][nt] = __builtin_amdgcn_mfma_f32_16x16x32_bf16(af[mt], bfr[nt],
                                                                      acc[mt][nt], 0, 0, 0);
    }
    if (EPI == 4 && col0 >= 2048) {
#pragma unroll
        for (int mt = 0; mt < 4; mt++) {
            int row_base = row0 + wy * 64 + mt * 16 + quad * 4;
            int bb = row_base >> 11, key0 = row_base & 2047;
#pragma unroll
            for (int nt = 0; nt < 4; nt++) {
                int vcol = col0 - 2048 + wx * 64 + nt * 16 + qm;
                int hh = vcol >> 6, dd = vcol & 63;
                bf16x4v pk;
#pragma unroll
                for (int r = 0; r < 4; r++) pk[r] = (bf16_t)acc[mt][nt][r];
                *(bf16x4v*)&Vt[(size_t)(((bb << 4) + hh) * 64 + dd) * 2048 + key0] = pk;
            }
        }
        return;
    }
    float qscale = (EPI == 4 && col0 < 1024) ? CLOG2 : 1.0f;
#pragma unroll
    for (int mt = 0; mt < 4; mt++) {
#pragma unroll
        for (int nt = 0; nt < 4; nt++) {
            int col = col0 + wx * 64 + nt * 16 + qm;
#pragma unroll
            for (int r = 0; r < 4; r++) {
                int row = row0 + wy * 64 + mt * 16 + quad * 4 + r;
                float v = acc[mt][nt][r];
                if (EPI == 2) { v += bias[col]; v = gelu_fast(v); }
                if (EPI == 4) C[(size_t)row * 2048 + col] = (OutT)(v * qscale);
                else          C[(size_t)row * N + col] = (OutT)v;
            }
        }
    }
}

// --------------------- GEMM 128x128 split-K, plain-store partials (z=2)
// No atomics: layer z stores its fp32 tile to P0/P1; the consumer kernel
// (ln_fuse / reduce_out) performs the z-reduction as part of a pass it
// already makes. Atomic RMW epilogue measured ~14 us per 8.4M atomics.
__global__ __launch_bounds__(256) void gemm_splitk_st_kernel(const bf16_t* __restrict__ A,
                                                             const bf16_t* __restrict__ BT,
                                                             float* __restrict__ P0,
                                                             float* __restrict__ P1,
                                                             int N, int Ktot, int Ksplit) {
    __shared__ __align__(16) bf16_t sA[2][128 * 32];
    __shared__ __align__(16) bf16_t sB[2][128 * 32];
    int tid = threadIdx.x;
    int lane = tid & 63, w = tid >> 6, wy = w >> 1, wx = w & 1;
    int qm = lane & 15, quad = lane >> 4;
    int row0 = blockIdx.x * 128, col0 = blockIdx.y * 128;
    size_t koff = (size_t)blockIdx.z * Ksplit;
    f32x4 acc[4][4] = {};
    int sf[2], sra[2], scol[2];
#pragma unroll
    for (int c = 0; c < 2; c++) {
        int f = tid * 8 + c * 2048;
        sf[c] = f;
        sra[c] = f >> 5;
        int ch = (f >> 3) & 3;
        scol[c] = ((ch ^ ((sra[c] >> 1) & 3)) << 3);
    }
    int aoff[4], boff[4];
#pragma unroll
    for (int t = 0; t < 4; t++) {
        int Ra = wy * 64 + t * 16 + qm;
        int Rb = wx * 64 + t * 16 + qm;
        aoff[t] = Ra * 32 + ((quad ^ ((Ra >> 1) & 3)) << 3);
        boff[t] = Rb * 32 + ((quad ^ ((Rb >> 1) & 3)) << 3);
    }
    const bf16_t* Ab = A  + (size_t)row0 * Ktot + koff;
    const bf16_t* Bb = BT + (size_t)col0 * Ktot + koff;
#pragma unroll
    for (int c = 0; c < 2; c++) {
        gload_lds16(Ab + (size_t)sra[c] * Ktot + scol[c], &sA[0][sf[c]]);
        gload_lds16(Bb + (size_t)sra[c] * Ktot + scol[c], &sB[0][sf[c]]);
    }
    for (int k0 = 0; k0 < Ksplit; k0 += 32) {
        int cur = (k0 >> 5) & 1;
        __syncthreads();
        int kn = k0 + 32;
        if (kn < Ksplit) {
#pragma unroll
            for (int c = 0; c < 2; c++) {
                gload_lds16(Ab + (size_t)sra[c] * Ktot + kn + scol[c], &sA[cur ^ 1][sf[c]]);
                gload_lds16(Bb + (size_t)sra[c] * Ktot + kn + scol[c], &sB[cur ^ 1][sf[c]]);
            }
        }
        bf16x8 af[4], bfr[4];
#pragma unroll
        for (int mt = 0; mt < 4; mt++) af[mt] = *(const bf16x8*)&sA[cur][aoff[mt]];
#pragma unroll
        for (int nt = 0; nt < 4; nt++) bfr[nt] = *(const bf16x8*)&sB[cur][boff[nt]];
#pragma unroll
        for (int mt = 0; mt < 4; mt++)
#pragma unroll
            for (int nt = 0; nt < 4; nt++)
                acc[mt][nt] = __builtin_amdgcn_mfma_f32_16x16x32_bf16(af[mt], bfr[nt],
                                                                      acc[mt][nt], 0, 0, 0);
    }
    float* P = blockIdx.z ? P1 : P0;
#pragma unroll
    for (int mt = 0; mt < 4; mt++) {
#pragma unroll
        for (int nt = 0; nt < 4; nt++) {
            int col = col0 + wx * 64 + nt * 16 + qm;
#pragma unroll
            for (int r = 0; r < 4; r++) {
                int row = row0 + wy * 64 + mt * 16 + quad * 4 + r;
                P[(size_t)row * N + col] = acc[mt][nt][r];
            }
        }
    }
}

// ---------------------------------------------------------------- attention
// Swapped-operand flash attention, KVBLK=128 (was 64): R3/R7 showed per-iter
// fixed cost (barrier + gload_lds vmcnt drain) dominates (~2325 cyc/wave-iter
// vs ~430 issued). Halving iteration count (32->16) amortizes it 2x.
// LDS 64KB/block -> still 2 blocks/CU (128<=160KB), 8 waves/CU preserved.
// Geometry per wave unchanged: 2 q-groups amortize each kf/vf LDS read.
__global__ __launch_bounds__(256) void attn_kernel(const bf16_t* __restrict__ QK,
                                                   const bf16_t* __restrict__ Vt,
                                                   bf16_t* __restrict__ O) {
    __shared__ __align__(16) bf16_t sK[2][128 * 64];   // [key 0..127][d 0..63] swizzled
    __shared__ __align__(16) bf16_t sV[2][64 * 128];   // [d 0..63][key 0..127] swizzled
    int tid = threadIdx.x, lane = tid & 63, w = tid >> 6;
    int qm = lane & 15, quad = lane >> 4;
    int q0 = blockIdx.x * 128 + w * 32;
    int bh = blockIdx.y, b = bh >> 4, h = bh & 15;

    const bf16_t* Qbase = QK + (size_t)(b * L_) * 2048 + h * 64;
    const bf16_t* Kbase = Qbase + 1024;
    const bf16_t* Vbase = Vt + (size_t)bh * 64 * 2048;

    bf16x8 qf[2][2];
#pragma unroll
    for (int g = 0; g < 2; g++) {
        const bf16_t* qp = Qbase + (size_t)(q0 + g * 16 + qm) * 2048 + quad * 8;
        qf[g][0] = *(const bf16x8*)qp;
        qf[g][1] = *(const bf16x8*)(qp + 32);
    }

    // K staging: 8192 elems = 128 rows x 64 cols; V: 64 rows x 128 cols.
    int ksf[4], ksr[4], ksc[4], vsf[4], vsr[4], vsc[4];
#pragma unroll
    for (int c = 0; c < 4; c++) {
        int f = tid * 8 + c * 2048;
        ksf[c] = f;
        ksr[c] = f >> 6;                       // key row 0..127
        ksc[c] = ((((f >> 3) & 7) ^ (ksr[c] & 7)) << 3);
        vsf[c] = f;
        vsr[c] = f >> 7;                       // d row 0..63
        vsc[c] = ((((f >> 3) & 15) ^ (vsr[c] & 7)) << 3);   // key offset 0..127
    }
#pragma unroll
    for (int c = 0; c < 4; c++) {
        gload_lds16(Kbase + (size_t)ksr[c] * 2048 + ksc[c], &sK[0][ksf[c]]);
        gload_lds16(Vbase + (size_t)vsr[c] * 2048 + vsc[c], &sV[0][vsf[c]]);
    }

    f32x4 o[2][4] = {};
    float l_[2] = {0.f, 0.f};

    int kfo[8][2], vfo[4][8];
#pragma unroll
    for (int kt = 0; kt < 8; kt++) {
        int row = kt * 16 + qm;                // key row 0..127
#pragma unroll
        for (int ks = 0; ks < 2; ks++)
            kfo[kt][ks] = row * 64 + ((((ks << 2) + quad) ^ (row & 7)) << 3);
#pragma unroll
        for (int dt = 0; dt < 4; dt++) {
            int vrow = dt * 16 + qm;           // d row 0..63
            int cw = (kt << 1) + (quad >> 1);  // key chunk 0..15
            vfo[dt][kt] = vrow * 128 + ((cw ^ (vrow & 7)) << 3) + ((quad & 1) << 2);
        }
    }

    for (int kv0 = 0; kv0 < L_; kv0 += 128) {
        int cur = (kv0 >> 7) & 1;
        __syncthreads();
        int kn = kv0 + 128;
        if (kn < L_) {
#pragma unroll
            for (int c = 0; c < 4; c++) {
                gload_lds16(Kbase + (size_t)(kn + ksr[c]) * 2048 + ksc[c], &sK[cur ^ 1][ksf[c]]);
                gload_lds16(Vbase + (size_t)vsr[c] * 2048 + kn + vsc[c], &sV[cur ^ 1][vsf[c]]);
            }
        }

        f32x4 s[2][8] = {};
        __builtin_amdgcn_s_setprio(1);
#pragma unroll
        for (int kt = 0; kt < 8; kt++)
#pragma unroll
            for (int ks = 0; ks < 2; ks++) {
                bf16x8 kf = *(const bf16x8*)&sK[cur][kfo[kt][ks]];
                s[0][kt] = __builtin_amdgcn_mfma_f32_16x16x32_bf16(kf, qf[0][ks], s[0][kt], 0, 0, 0);
                s[1][kt] = __builtin_amdgcn_mfma_f32_16x16x32_bf16(kf, qf[1][ks], s[1][kt], 0, 0, 0);
            }
        __builtin_amdgcn_s_setprio(0);

        s16x4 pf[2][8];
#pragma unroll
        for (int g = 0; g < 2; g++) {
            float sum = l_[g];
#pragma unroll
            for (int kt = 0; kt < 8; kt++) {
                union { bf16x4v b; s16x4 i; } u;
#pragma unroll
                for (int r = 0; r < 4; r++) {
                    float p = fast_exp2(s[g][kt][r]);
                    sum += p;
                    u.b[r] = (bf16_t)p;
                }
                pf[g][kt] = u.i;
            }
            l_[g] = sum;
        }

        __builtin_amdgcn_s_setprio(1);
#pragma unroll
        for (int dt = 0; dt < 4; dt++)
#pragma unroll
            for (int kt = 0; kt < 8; kt++) {
                s16x4 vf = *(const s16x4*)&sV[cur][vfo[dt][kt]];
                o[0][dt] = __builtin_amdgcn_mfma_f32_16x16x16bf16_1k(vf, pf[0][kt], o[0][dt], 0, 0, 0);
                o[1][dt] = __builtin_amdgcn_mfma_f32_16x16x16bf16_1k(vf, pf[1][kt], o[1][dt], 0, 0, 0);
            }
        __builtin_amdgcn_s_setprio(0);
    }

#pragma unroll
    for (int g = 0; g < 2; g++) {
        float lt = l_[g];
        lt += __shfl_xor(lt, 16);
        lt += __shfl_xor(lt, 32);
        float rl = 1.0f / lt;
        size_t row = (size_t)(b * L_ + q0 + g * 16 + qm);
#pragma unroll
        for (int dt = 0; dt < 4; dt++) {
            bf16x4v pk;
#pragma unroll
            for (int r = 0; r < 4; r++) pk[r] = (bf16_t)(o[g][dt][r] * rl);
            *(bf16x4v*)&O[row * D_ + h * 64 + dt * 16 + quad * 4] = pk;
        }
    }
}

// ---------------------------------------------------------------- launch

extern "C" void kernel_launch(void* const* d_in, const int* in_sizes, int n_in,
                              void* d_out, int out_size, void* d_ws, size_t ws_size,
                              hipStream_t stream) {
    const float* x   = (const float*)d_in[0];
    const float* pos = (const float*)d_in[1];
    const float* g1  = (const float*)d_in[2];
    const float* be1 = (const float*)d_in[3];
    const float* Wq  = (const float*)d_in[4];
    const float* Wk  = (const float*)d_in[5];
    const float* Wv  = (const float*)d_in[6];
    const float* Wo  = (const float*)d_in[7];
    const float* bo  = (const float*)d_in[8];
    const float* g2  = (const float*)d_in[9];
    const float* be2 = (const float*)d_in[10];
    const float* W1  = (const float*)d_in[11];
    const float* b1m = (const float*)d_in[12];
    const float* W2  = (const float*)d_in[13];
    const float* b2m = (const float*)d_in[14];

    char* ws = (char*)d_ws;
    const size_t MB = 1ull << 20;
    bf16_t* W2T   = (bf16_t*)(ws + 0);        //  0-8   live until FF2
    float*  x2    = (float*) (ws + 8 * MB);   //  8-24  live ln_fuse..reduce_out
    bf16_t* qk    = (bf16_t*)(ws + 24 * MB);  // 24-40  dead after attn
    bf16_t* Vt    = (bf16_t*)(ws + 40 * MB);  // 40-48  dead after attn
    bf16_t* hb    = (bf16_t*)(ws + 48 * MB);  // 48-56  dead after QKV gemm
    float*  Pwo0  = (float*) (ws + 24 * MB);  // 24-40  Wo partial z=0 (over qk)
    float*  Pwo1  = (float*) (ws + 40 * MB);  // 40-56  Wo partial z=1 (over Vt+hb)
    bf16_t* attnO = (bf16_t*)(ws + 56 * MB);  // 56-64  dead after Wo-proj
    bf16_t* mb    = (bf16_t*)(ws + 56 * MB);  // 56-64  written by ln_fuse
    bf16_t* ff1   = (bf16_t*)(ws + 24 * MB);  // 24-56  over Pwo (dead after ln_fuse)
    bf16_t* W1T   = (bf16_t*)(ws + 64 * MB);  // 64-72  dead after FF1
    float*  Pff1  = (float*) (ws + 56 * MB);  // 56-72  FF2 partial z=1 (over mb+W1T)
    bf16_t* WqkvT = (bf16_t*)(ws + 72 * MB);  // 72-78  dead after QKV gemm
    bf16_t* WoT   = (bf16_t*)(ws + 78 * MB);  // 78-80  dead after Wo-proj

    dim3 tt(16, 16);
    transpose_qkvo_kernel<<<dim3(16, 16, 4), tt, 0, stream>>>(Wq, Wk, Wv, Wo, WqkvT, WoT);
    transpose_bf16_kernel<<<dim3(64, 16), tt, 0, stream>>>(W1, W1T, D_, FF_);
    transpose_bf16_kernel<<<dim3(16, 64), tt, 0, stream>>>(W2, W2T, FF_, D_);

    ln_kernel<<<M_TOT, 256, 0, stream>>>(x, pos, g1, be1, hb);

    gemm_kernel<4, bf16_t><<<dim3(32, 24), 256, 0, stream>>>(hb, WqkvT, qk, nullptr,
                                                             Vt, M_TOT, 3072, D_);

    attn_kernel<<<dim3(16, 32), 256, 0, stream>>>(qk, Vt, attnO);

    // Wo projection: partials, no atomics
    gemm_splitk_st_kernel<<<dim3(32, 8, 2), 256, 0, stream>>>(attnO, WoT, Pwo0, Pwo1,
                                                              D_, D_, D_ / 2);

    // x2 = x + bo + Pwo0 + Pwo1 ; mb = LN(x2)
    ln_fuse_kernel<<<M_TOT, 256, 0, stream>>>(x, bo, Pwo0, Pwo1, g2, be2, x2, mb);

    gemm_kernel<2, bf16_t><<<dim3(32, 32), 256, 0, stream>>>(mb, W1T, ff1, b1m,
                                                             nullptr, M_TOT, FF_, D_);

    // FF2: partial z=0 straight into d_out, z=1 into workspace
    gemm_splitk_st_kernel<<<dim3(32, 8, 2), 256, 0, stream>>>(ff1, W2T, (float*)d_out,
                                                              Pff1, D_, FF_, FF_ / 2);

    // d_out = x2 + b2m + P0(d_out) + Pff1
    reduce_out_kernel<<<M_TOT * D_ / 1024, 256, 0, stream>>>(x2, b2m, Pff1, (float*)d_out);

    (void)in_sizes; (void)n_in; (void)out_size; (void)ws_size;
}

// Round 12
// 365.344 us; speedup vs baseline: 1.0149x; 1.0149x over previous
//
#include <hip/hip_runtime.h>
#include <hip/hip_bf16.h>
#include <cstdint>

typedef __bf16 bf16_t;
typedef __bf16 bf16x8 __attribute__((ext_vector_type(8)));
typedef __bf16 bf16x4v __attribute__((ext_vector_type(4)));
typedef short s16x4 __attribute__((ext_vector_type(4)));
typedef float f32x4 __attribute__((ext_vector_type(4)));

#define B_ 2
#define L_ 2048
#define D_ 1024
#define H_ 16
#define DH_ 64
#define FF_ 4096
#define M_TOT (B_*L_)

// 0.125 (DH^-0.5) * log2(e): folded into Q at the QKV epilogue
#define CLOG2 0.18033688011112042f

// ---------------------------------------------------------------- utilities

__device__ __forceinline__ void gload_lds16(const void* g, void* l) {
    __builtin_amdgcn_global_load_lds((__attribute__((address_space(1))) void*)g,
                                     (__attribute__((address_space(3))) void*)l,
                                     16, 0, 0);
}

__device__ __forceinline__ float fast_exp2(float v) {
    return __builtin_amdgcn_exp2f(v);
}

// tanh-form GELU: 0.5x(1+tanh(0.79788456(x+0.044715x^3))), tanh via exp2+rcp.
__device__ __forceinline__ float gelu_fast(float x) {
    float x3 = x * x * x;
    float y  = fmaf(0.044715f, x3, x);
    float e  = fast_exp2(y * 2.3022213f);   // exp(2*0.79788456*y)
    float t  = fmaf(-2.0f, __builtin_amdgcn_rcpf(e + 1.0f), 1.0f);
    return 0.5f * x * (1.0f + t);
}

// ------------------------------------------------- weight transpose + cast
// 64x64 tiles, float4 reads, bf16x4 packed writes (saved ~8us vs 32x32 scalar).
__global__ void transpose_bf16_kernel(const float* __restrict__ W, bf16_t* __restrict__ WT,
                                      int K, int N) {
    __shared__ float t[64][65];
    int tx = threadIdx.x, ty = threadIdx.y;
    int n0 = blockIdx.x * 64, k0 = blockIdx.y * 64;
#pragma unroll
    for (int i = 0; i < 4; i++) {
        int r = ty * 4 + i;
        float4 v = *(const float4*)(W + (size_t)(k0 + r) * N + n0 + tx * 4);
        t[r][tx * 4 + 0] = v.x; t[r][tx * 4 + 1] = v.y;
        t[r][tx * 4 + 2] = v.z; t[r][tx * 4 + 3] = v.w;
    }
    __syncthreads();
#pragma unroll
    for (int i = 0; i < 4; i++) {
        int r = ty * 4 + i;
        bf16x4v pk;
#pragma unroll
        for (int j = 0; j < 4; j++) pk[j] = (bf16_t)t[tx * 4 + j][r];
        *(bf16x4v*)(WT + (size_t)(n0 + r) * K + k0 + tx * 4) = pk;
    }
}

__global__ void transpose_qkvo_kernel(const float* __restrict__ Wq, const float* __restrict__ Wk,
                                      const float* __restrict__ Wv, const float* __restrict__ Wo,
                                      bf16_t* __restrict__ WqkvT, bf16_t* __restrict__ WoT) {
    int z = blockIdx.z;
    const float* W = (z == 0) ? Wq : (z == 1) ? Wk : (z == 2) ? Wv : Wo;
    bf16_t* dst = (z < 3) ? (WqkvT + (size_t)z * 1024 * 1024) : WoT;
    __shared__ float t[64][65];
    int tx = threadIdx.x, ty = threadIdx.y;
    int n0 = blockIdx.x * 64, k0 = blockIdx.y * 64;
#pragma unroll
    for (int i = 0; i < 4; i++) {
        int r = ty * 4 + i;
        float4 v = *(const float4*)(W + (size_t)(k0 + r) * D_ + n0 + tx * 4);
        t[r][tx * 4 + 0] = v.x; t[r][tx * 4 + 1] = v.y;
        t[r][tx * 4 + 2] = v.z; t[r][tx * 4 + 3] = v.w;
    }
    __syncthreads();
#pragma unroll
    for (int i = 0; i < 4; i++) {
        int r = ty * 4 + i;
        bf16x4v pk;
#pragma unroll
        for (int j = 0; j < 4; j++) pk[j] = (bf16_t)t[tx * 4 + j][r];
        *(bf16x4v*)(dst + (size_t)(n0 + r) * D_ + k0 + tx * 4) = pk;
    }
}

// ---------------------------------------------------------------- layernorm
__global__ __launch_bounds__(256) void ln_kernel(const float* __restrict__ x,
                                                 const float* __restrict__ pos,
                                                 const float* __restrict__ g,
                                                 const float* __restrict__ beta,
                                                 bf16_t* __restrict__ out) {
    int row = blockIdx.x, tid = threadIdx.x;
    const float* xr = x + (size_t)row * D_;
    float v[4];
    float s = 0.f, sq = 0.f;
#pragma unroll
    for (int i = 0; i < 4; i++) {
        float a = xr[tid + 256 * i];
        v[i] = a; s += a; sq += a * a;
    }
#pragma unroll
    for (int o = 32; o > 0; o >>= 1) { s += __shfl_xor(s, o); sq += __shfl_xor(sq, o); }
    __shared__ float red[8];
    int wid = tid >> 6;
    if ((tid & 63) == 0) { red[wid] = s; red[4 + wid] = sq; }
    __syncthreads();
    s  = red[0] + red[1] + red[2] + red[3];
    sq = red[4] + red[5] + red[6] + red[7];
    float mu  = s * (1.f / D_);
    float var = sq * (1.f / D_) - mu * mu;
    float rs  = rsqrtf(var + 1e-5f);
    int l = row & (L_ - 1);
#pragma unroll
    for (int i = 0; i < 4; i++) {
        int c = tid + 256 * i;
        float hv = (v[i] - mu) * rs * g[c] + beta[c];
        if (pos) hv += pos[(size_t)l * D_ + c];
        out[(size_t)row * D_ + c] = (bf16_t)hv;
    }
}

// ----------------- fused: x2 = x + bo + P0 + P1 ; mb = LN(x2)*g+beta (bf16)
__global__ __launch_bounds__(256) void ln_fuse_kernel(const float* __restrict__ x,
                                                      const float* __restrict__ bo,
                                                      const float* __restrict__ P0,
                                                      const float* __restrict__ P1,
                                                      const float* __restrict__ g,
                                                      const float* __restrict__ beta,
                                                      float* __restrict__ x2,
                                                      bf16_t* __restrict__ out) {
    int row = blockIdx.x, tid = threadIdx.x;
    size_t base = (size_t)row * D_;
    float v[4];
    float s = 0.f, sq = 0.f;
#pragma unroll
    for (int i = 0; i < 4; i++) {
        int c = tid + 256 * i;
        float a = x[base + c] + bo[c] + P0[base + c] + P1[base + c];
        v[i] = a; s += a; sq += a * a;
        x2[base + c] = a;
    }
#pragma unroll
    for (int o = 32; o > 0; o >>= 1) { s += __shfl_xor(s, o); sq += __shfl_xor(sq, o); }
    __shared__ float red[8];
    int wid = tid >> 6;
    if ((tid & 63) == 0) { red[wid] = s; red[4 + wid] = sq; }
    __syncthreads();
    s  = red[0] + red[1] + red[2] + red[3];
    sq = red[4] + red[5] + red[6] + red[7];
    float mu  = s * (1.f / D_);
    float var = sq * (1.f / D_) - mu * mu;
    float rs  = rsqrtf(var + 1e-5f);
#pragma unroll
    for (int i = 0; i < 4; i++) {
        int c = tid + 256 * i;
        out[base + c] = (bf16_t)((v[i] - mu) * rs * g[c] + beta[c]);
    }
}

// ------------- final: dout = x2 + bias + P0(in dout) + P1  (vectorized)
__global__ __launch_bounds__(256) void reduce_out_kernel(const float* __restrict__ x2,
                                                         const float* __restrict__ bias,
                                                         const float* __restrict__ P1,
                                                         float* __restrict__ dout) {
    int i = (blockIdx.x * 256 + threadIdx.x) * 4;
    float4 a  = *(const float4*)(x2 + i);
    float4 bv = *(const float4*)(bias + (i & (D_ - 1)));
    float4 p0 = *(const float4*)(dout + i);
    float4 p1 = *(const float4*)(P1 + i);
    a.x += bv.x + p0.x + p1.x;
    a.y += bv.y + p0.y + p1.y;
    a.z += bv.z + p0.z + p1.z;
    a.w += bv.w + p0.w + p1.w;
    *(float4*)(dout + i) = a;
}

// ------------------------------------- GEMM 128x128, BK=32, double-buffered
// XOR source-chunk swizzle on staging (lane-linear LDS dest); read-side
// swizzle (row>>1)&3 -> 2-way max (free), verified SQ_LDS_BANK_CONFLICT=0.
// EPI: 2 = +bias,GELU (bf16 out); 4 = fused QKV (q cols scaled by CLOG2;
//      cols<2048 -> qk stride 2048; cols>=2048 -> Vt transposed)
template <int EPI, typename OutT>
__global__ __launch_bounds__(256) void gemm_kernel(const bf16_t* __restrict__ A,
                                                   const bf16_t* __restrict__ BT,
                                                   OutT* __restrict__ C,
                                                   const float* __restrict__ bias,
                                                   bf16_t* __restrict__ Vt,
                                                   int M, int N, int K) {
    __shared__ __align__(16) bf16_t sA[2][128 * 32];
    __shared__ __align__(16) bf16_t sB[2][128 * 32];
    int tid = threadIdx.x;
    int lane = tid & 63, w = tid >> 6, wy = w >> 1, wx = w & 1;
    int qm = lane & 15, quad = lane >> 4;
    int row0 = blockIdx.x * 128, col0 = blockIdx.y * 128;
    f32x4 acc[4][4] = {};
    int sf[2], sra[2], scol[2];
#pragma unroll
    for (int c = 0; c < 2; c++) {
        int f = tid * 8 + c * 2048;
        sf[c] = f;
        sra[c] = f >> 5;
        int ch = (f >> 3) & 3;
        scol[c] = ((ch ^ ((sra[c] >> 1) & 3)) << 3);
    }
    int aoff[4], boff[4];
#pragma unroll
    for (int t = 0; t < 4; t++) {
        int Ra = wy * 64 + t * 16 + qm;
        int Rb = wx * 64 + t * 16 + qm;
        aoff[t] = Ra * 32 + ((quad ^ ((Ra >> 1) & 3)) << 3);
        boff[t] = Rb * 32 + ((quad ^ ((Rb >> 1) & 3)) << 3);
    }
    const bf16_t* Ab = A  + (size_t)row0 * K;
    const bf16_t* Bb = BT + (size_t)col0 * K;
#pragma unroll
    for (int c = 0; c < 2; c++) {
        gload_lds16(Ab + (size_t)sra[c] * K + scol[c], &sA[0][sf[c]]);
        gload_lds16(Bb + (size_t)sra[c] * K + scol[c], &sB[0][sf[c]]);
    }
    for (int k0 = 0; k0 < K; k0 += 32) {
        int cur = (k0 >> 5) & 1;
        __syncthreads();
        int kn = k0 + 32;
        if (kn < K) {
#pragma unroll
            for (int c = 0; c < 2; c++) {
                gload_lds16(Ab + (size_t)sra[c] * K + kn + scol[c], &sA[cur ^ 1][sf[c]]);
                gload_lds16(Bb + (size_t)sra[c] * K + kn + scol[c], &sB[cur ^ 1][sf[c]]);
            }
        }
        bf16x8 af[4], bfr[4];
#pragma unroll
        for (int mt = 0; mt < 4; mt++) af[mt] = *(const bf16x8*)&sA[cur][aoff[mt]];
#pragma unroll
        for (int nt = 0; nt < 4; nt++) bfr[nt] = *(const bf16x8*)&sB[cur][boff[nt]];
#pragma unroll
        for (int mt = 0; mt < 4; mt++)
#pragma unroll
            for (int nt = 0; nt < 4; nt++)
                acc[mt][nt] = __builtin_amdgcn_mfma_f32_16x16x32_bf16(af[mt], bfr[nt],
                                                                      acc[mt][nt], 0, 0, 0);
    }
    if (EPI == 4 && col0 >= 2048) {
#pragma unroll
        for (int mt = 0; mt < 4; mt++) {
            int row_base = row0 + wy * 64 + mt * 16 + quad * 4;
            int bb = row_base >> 11, key0 = row_base & 2047;
#pragma unroll
            for (int nt = 0; nt < 4; nt++) {
                int vcol = col0 - 2048 + wx * 64 + nt * 16 + qm;
                int hh = vcol >> 6, dd = vcol & 63;
                bf16x4v pk;
#pragma unroll
                for (int r = 0; r < 4; r++) pk[r] = (bf16_t)acc[mt][nt][r];
                *(bf16x4v*)&Vt[(size_t)(((bb << 4) + hh) * 64 + dd) * 2048 + key0] = pk;
            }
        }
        return;
    }
    float qscale = (EPI == 4 && col0 < 1024) ? CLOG2 : 1.0f;
#pragma unroll
    for (int mt = 0; mt < 4; mt++) {
#pragma unroll
        for (int nt = 0; nt < 4; nt++) {
            int col = col0 + wx * 64 + nt * 16 + qm;
#pragma unroll
            for (int r = 0; r < 4; r++) {
                int row = row0 + wy * 64 + mt * 16 + quad * 4 + r;
                float v = acc[mt][nt][r];
                if (EPI == 2) { v += bias[col]; v = gelu_fast(v); }
                if (EPI == 4) C[(size_t)row * 2048 + col] = (OutT)(v * qscale);
                else          C[(size_t)row * N + col] = (OutT)v;
            }
        }
    }
}

// ------------------- GEMM 256x256, BK=32, double-buffered, 512 threads
// Parameter scale-up of the proven 2-phase template: 8 waves (2Mx4N), each
// owns 128x64. 2x arithmetic intensity per staged byte (32 MFMA : 12 ds_read
// vs 16:8) and 2x MFMA per barrier. m248 measured 2ph 256^2 @K=1024 = 666 TF
// vs our 128^2 = 476 TF. Same staging/read swizzle involution as 128^2.
// LDS 64KB; VGPR ~210 -> 1 block/CU (8 waves). EPI: bias+GELU, bf16 out.
__global__ __launch_bounds__(512, 2) void gemm256_gelu_kernel(const bf16_t* __restrict__ A,
                                                              const bf16_t* __restrict__ BT,
                                                              bf16_t* __restrict__ C,
                                                              const float* __restrict__ bias,
                                                              int N, int K) {
    __shared__ __align__(16) bf16_t sA[2][256 * 32];
    __shared__ __align__(16) bf16_t sB[2][256 * 32];
    int tid = threadIdx.x;
    int lane = tid & 63, w = tid >> 6, wy = w >> 2, wx = w & 3;
    int qm = lane & 15, quad = lane >> 4;
    int row0 = blockIdx.x * 256, col0 = blockIdx.y * 256;
    f32x4 acc[8][4] = {};
    int sf[2], sra[2], scol[2];
#pragma unroll
    for (int c = 0; c < 2; c++) {
        int f = tid * 8 + c * 4096;
        sf[c] = f;
        sra[c] = f >> 5;                         // row 0..255
        int ch = (f >> 3) & 3;
        scol[c] = ((ch ^ ((sra[c] >> 1) & 3)) << 3);
    }
    int aoff[8], boff[4];
#pragma unroll
    for (int t = 0; t < 8; t++) {
        int Ra = wy * 128 + t * 16 + qm;
        aoff[t] = Ra * 32 + ((quad ^ ((Ra >> 1) & 3)) << 3);
    }
#pragma unroll
    for (int t = 0; t < 4; t++) {
        int Rb = wx * 64 + t * 16 + qm;
        boff[t] = Rb * 32 + ((quad ^ ((Rb >> 1) & 3)) << 3);
    }
    const bf16_t* Ab = A  + (size_t)row0 * K;
    const bf16_t* Bb = BT + (size_t)col0 * K;
#pragma unroll
    for (int c = 0; c < 2; c++) {
        gload_lds16(Ab + (size_t)sra[c] * K + scol[c], &sA[0][sf[c]]);
        gload_lds16(Bb + (size_t)sra[c] * K + scol[c], &sB[0][sf[c]]);
    }
    for (int k0 = 0; k0 < K; k0 += 32) {
        int cur = (k0 >> 5) & 1;
        __syncthreads();
        int kn = k0 + 32;
        if (kn < K) {
#pragma unroll
            for (int c = 0; c < 2; c++) {
                gload_lds16(Ab + (size_t)sra[c] * K + kn + scol[c], &sA[cur ^ 1][sf[c]]);
                gload_lds16(Bb + (size_t)sra[c] * K + kn + scol[c], &sB[cur ^ 1][sf[c]]);
            }
        }
        bf16x8 bfr[4];
#pragma unroll
        for (int nt = 0; nt < 4; nt++) bfr[nt] = *(const bf16x8*)&sB[cur][boff[nt]];
#pragma unroll
        for (int mt = 0; mt < 8; mt++) {
            bf16x8 af = *(const bf16x8*)&sA[cur][aoff[mt]];
#pragma unroll
            for (int nt = 0; nt < 4; nt++)
                acc[mt][nt] = __builtin_amdgcn_mfma_f32_16x16x32_bf16(af, bfr[nt],
                                                                      acc[mt][nt], 0, 0, 0);
        }
    }
#pragma unroll
    for (int mt = 0; mt < 8; mt++) {
#pragma unroll
        for (int nt = 0; nt < 4; nt++) {
            int col = col0 + wx * 64 + nt * 16 + qm;
            float bv = bias[col];
#pragma unroll
            for (int r = 0; r < 4; r++) {
                int row = row0 + wy * 128 + mt * 16 + quad * 4 + r;
                C[(size_t)row * N + col] = (bf16_t)gelu_fast(acc[mt][nt][r] + bv);
            }
        }
    }
}

// --------------------- GEMM 128x128 split-K, plain-store partials (z=2)
// No atomics: layer z stores its fp32 tile to P0/P1; the consumer kernel
// (ln_fuse / reduce_out) performs the z-reduction as part of a pass it
// already makes. Atomic RMW epilogue measured ~14 us per 8.4M atomics.
__global__ __launch_bounds__(256) void gemm_splitk_st_kernel(const bf16_t* __restrict__ A,
                                                             const bf16_t* __restrict__ BT,
                                                             float* __restrict__ P0,
                                                             float* __restrict__ P1,
                                                             int N, int Ktot, int Ksplit) {
    __shared__ __align__(16) bf16_t sA[2][128 * 32];
    __shared__ __align__(16) bf16_t sB[2][128 * 32];
    int tid = threadIdx.x;
    int lane = tid & 63, w = tid >> 6, wy = w >> 1, wx = w & 1;
    int qm = lane & 15, quad = lane >> 4;
    int row0 = blockIdx.x * 128, col0 = blockIdx.y * 128;
    size_t koff = (size_t)blockIdx.z * Ksplit;
    f32x4 acc[4][4] = {};
    int sf[2], sra[2], scol[2];
#pragma unroll
    for (int c = 0; c < 2; c++) {
        int f = tid * 8 + c * 2048;
        sf[c] = f;
        sra[c] = f >> 5;
        int ch = (f >> 3) & 3;
        scol[c] = ((ch ^ ((sra[c] >> 1) & 3)) << 3);
    }
    int aoff[4], boff[4];
#pragma unroll
    for (int t = 0; t < 4; t++) {
        int Ra = wy * 64 + t * 16 + qm;
        int Rb = wx * 64 + t * 16 + qm;
        aoff[t] = Ra * 32 + ((quad ^ ((Ra >> 1) & 3)) << 3);
        boff[t] = Rb * 32 + ((quad ^ ((Rb >> 1) & 3)) << 3);
    }
    const bf16_t* Ab = A  + (size_t)row0 * Ktot + koff;
    const bf16_t* Bb = BT + (size_t)col0 * Ktot + koff;
#pragma unroll
    for (int c = 0; c < 2; c++) {
        gload_lds16(Ab + (size_t)sra[c] * Ktot + scol[c], &sA[0][sf[c]]);
        gload_lds16(Bb + (size_t)sra[c] * Ktot + scol[c], &sB[0][sf[c]]);
    }
    for (int k0 = 0; k0 < Ksplit; k0 += 32) {
        int cur = (k0 >> 5) & 1;
        __syncthreads();
        int kn = k0 + 32;
        if (kn < Ksplit) {
#pragma unroll
            for (int c = 0; c < 2; c++) {
                gload_lds16(Ab + (size_t)sra[c] * Ktot + kn + scol[c], &sA[cur ^ 1][sf[c]]);
                gload_lds16(Bb + (size_t)sra[c] * Ktot + kn + scol[c], &sB[cur ^ 1][sf[c]]);
            }
        }
        bf16x8 af[4], bfr[4];
#pragma unroll
        for (int mt = 0; mt < 4; mt++) af[mt] = *(const bf16x8*)&sA[cur][aoff[mt]];
#pragma unroll
        for (int nt = 0; nt < 4; nt++) bfr[nt] = *(const bf16x8*)&sB[cur][boff[nt]];
#pragma unroll
        for (int mt = 0; mt < 4; mt++)
#pragma unroll
            for (int nt = 0; nt < 4; nt++)
                acc[mt][nt] = __builtin_amdgcn_mfma_f32_16x16x32_bf16(af[mt], bfr[nt],
                                                                      acc[mt][nt], 0, 0, 0);
    }
    float* P = blockIdx.z ? P1 : P0;
#pragma unroll
    for (int mt = 0; mt < 4; mt++) {
#pragma unroll
        for (int nt = 0; nt < 4; nt++) {
            int col = col0 + wx * 64 + nt * 16 + qm;
#pragma unroll
            for (int r = 0; r < 4; r++) {
                int row = row0 + wy * 64 + mt * 16 + quad * 4 + r;
                P[(size_t)row * N + col] = acc[mt][nt][r];
            }
        }
    }
}

// ---------------------------------------------------------------- attention
// Swapped-operand flash attention — R3/R7 structure (proven 61.5us):
// KVBLK=64, 4 waves x 32 Q-rows (2 q-groups/wave), 2 blocks/CU, 8 waves/CU.
// Geometry search complete: 1-qg (66.5), 4-qg (95.8), KVBLK=128 (72.4) all
// regress — drain cost scales with staged bytes, and 8 waves/CU with 2-qg
// amortization is the joint optimum of this 2-barrier schedule.
__global__ __launch_bounds__(256) void attn_kernel(const bf16_t* __restrict__ QK,
                                                   const bf16_t* __restrict__ Vt,
                                                   bf16_t* __restrict__ O) {
    __shared__ __align__(16) bf16_t sK[2][64 * 64];
    __shared__ __align__(16) bf16_t sV[2][64 * 64];
    int tid = threadIdx.x, lane = tid & 63, w = tid >> 6;
    int qm = lane & 15, quad = lane >> 4;
    int q0 = blockIdx.x * 128 + w * 32;
    int bh = blockIdx.y, b = bh >> 4, h = bh & 15;

    const bf16_t* Qbase = QK + (size_t)(b * L_) * 2048 + h * 64;
    const bf16_t* Kbase = Qbase + 1024;
    const bf16_t* Vbase = Vt + (size_t)bh * 64 * 2048;

    bf16x8 qf[2][2];
#pragma unroll
    for (int g = 0; g < 2; g++) {
        const bf16_t* qp = Qbase + (size_t)(q0 + g * 16 + qm) * 2048 + quad * 8;
        qf[g][0] = *(const bf16x8*)qp;
        qf[g][1] = *(const bf16x8*)(qp + 32);
    }

    int f0 = tid * 8, f1 = f0 + 2048;
    int r0 = f0 >> 6, sc0 = ((((f0 >> 3) & 7) ^ (r0 & 7)) << 3);
    int r1 = f1 >> 6, sc1 = ((((f1 >> 3) & 7) ^ (r1 & 7)) << 3);

    gload_lds16(Kbase + (size_t)r0 * 2048 + sc0, &sK[0][f0]);
    gload_lds16(Kbase + (size_t)r1 * 2048 + sc1, &sK[0][f1]);
    gload_lds16(Vbase + (size_t)r0 * 2048 + sc0, &sV[0][f0]);
    gload_lds16(Vbase + (size_t)r1 * 2048 + sc1, &sV[0][f1]);

    f32x4 o[2][4] = {};
    float l_[2] = {0.f, 0.f};

    int kfo[4][2], vfo[4][4];
#pragma unroll
    for (int kt = 0; kt < 4; kt++) {
#pragma unroll
        for (int ks = 0; ks < 2; ks++) {
            int row = kt * 16 + qm;
            kfo[kt][ks] = row * 64 + ((((ks << 2) + quad) ^ (row & 7)) << 3);
        }
#pragma unroll
        for (int dt = 0; dt < 4; dt++) {
            int row = dt * 16 + qm;
            int cw = (kt << 1) + (quad >> 1);
            vfo[dt][kt] = row * 64 + ((cw ^ (row & 7)) << 3) + ((quad & 1) << 2);
        }
    }

    for (int kv0 = 0; kv0 < L_; kv0 += 64) {
        int cur = (kv0 >> 6) & 1;
        __syncthreads();
        int kn = kv0 + 64;
        if (kn < L_) {
            gload_lds16(Kbase + (size_t)(kn + r0) * 2048 + sc0, &sK[cur ^ 1][f0]);
            gload_lds16(Kbase + (size_t)(kn + r1) * 2048 + sc1, &sK[cur ^ 1][f1]);
            gload_lds16(Vbase + (size_t)r0 * 2048 + kn + sc0, &sV[cur ^ 1][f0]);
            gload_lds16(Vbase + (size_t)r1 * 2048 + kn + sc1, &sV[cur ^ 1][f1]);
        }

        bf16x8 kf[4][2];
#pragma unroll
        for (int kt = 0; kt < 4; kt++)
#pragma unroll
            for (int ks = 0; ks < 2; ks++)
                kf[kt][ks] = *(const bf16x8*)&sK[cur][kfo[kt][ks]];
        f32x4 s[2][4] = {};
        __builtin_amdgcn_s_setprio(1);
#pragma unroll
        for (int kt = 0; kt < 4; kt++)
#pragma unroll
            for (int ks = 0; ks < 2; ks++) {
                s[0][kt] = __builtin_amdgcn_mfma_f32_16x16x32_bf16(kf[kt][ks], qf[0][ks], s[0][kt], 0, 0, 0);
                s[1][kt] = __builtin_amdgcn_mfma_f32_16x16x32_bf16(kf[kt][ks], qf[1][ks], s[1][kt], 0, 0, 0);
            }
        __builtin_amdgcn_s_setprio(0);

        s16x4 pf[2][4];
#pragma unroll
        for (int g = 0; g < 2; g++) {
            float sum = l_[g];
#pragma unroll
            for (int kt = 0; kt < 4; kt++) {
                union { bf16x4v b; s16x4 i; } u;
#pragma unroll
                for (int r = 0; r < 4; r++) {
                    float p = fast_exp2(s[g][kt][r]);
                    sum += p;
                    u.b[r] = (bf16_t)p;
                }
                pf[g][kt] = u.i;
            }
            l_[g] = sum;
        }

        __builtin_amdgcn_s_setprio(1);
#pragma unroll
        for (int dt = 0; dt < 4; dt++)
#pragma unroll
            for (int kt = 0; kt < 4; kt++) {
                s16x4 vf = *(const s16x4*)&sV[cur][vfo[dt][kt]];
                o[0][dt] = __builtin_amdgcn_mfma_f32_16x16x16bf16_1k(vf, pf[0][kt], o[0][dt], 0, 0, 0);
                o[1][dt] = __builtin_amdgcn_mfma_f32_16x16x16bf16_1k(vf, pf[1][kt], o[1][dt], 0, 0, 0);
            }
        __builtin_amdgcn_s_setprio(0);
    }

#pragma unroll
    for (int g = 0; g < 2; g++) {
        float lt = l_[g];
        lt += __shfl_xor(lt, 16);
        lt += __shfl_xor(lt, 32);
        float rl = 1.0f / lt;
        size_t row = (size_t)(b * L_ + q0 + g * 16 + qm);
#pragma unroll
        for (int dt = 0; dt < 4; dt++) {
            bf16x4v pk;
#pragma unroll
            for (int r = 0; r < 4; r++) pk[r] = (bf16_t)(o[g][dt][r] * rl);
            *(bf16x4v*)&O[row * D_ + h * 64 + dt * 16 + quad * 4] = pk;
        }
    }
}

// ---------------------------------------------------------------- launch

extern "C" void kernel_launch(void* const* d_in, const int* in_sizes, int n_in,
                              void* d_out, int out_size, void* d_ws, size_t ws_size,
                              hipStream_t stream) {
    const float* x   = (const float*)d_in[0];
    const float* pos = (const float*)d_in[1];
    const float* g1  = (const float*)d_in[2];
    const float* be1 = (const float*)d_in[3];
    const float* Wq  = (const float*)d_in[4];
    const float* Wk  = (const float*)d_in[5];
    const float* Wv  = (const float*)d_in[6];
    const float* Wo  = (const float*)d_in[7];
    const float* bo  = (const float*)d_in[8];
    const float* g2  = (const float*)d_in[9];
    const float* be2 = (const float*)d_in[10];
    const float* W1  = (const float*)d_in[11];
    const float* b1m = (const float*)d_in[12];
    const float* W2  = (const float*)d_in[13];
    const float* b2m = (const float*)d_in[14];

    char* ws = (char*)d_ws;
    const size_t MB = 1ull << 20;
    bf16_t* W2T   = (bf16_t*)(ws + 0);        //  0-8   live until FF2
    float*  x2    = (float*) (ws + 8 * MB);   //  8-24  live ln_fuse..reduce_out
    bf16_t* qk    = (bf16_t*)(ws + 24 * MB);  // 24-40  dead after attn
    bf16_t* Vt    = (bf16_t*)(ws + 40 * MB);  // 40-48  dead after attn
    bf16_t* hb    = (bf16_t*)(ws + 48 * MB);  // 48-56  dead after QKV gemm
    float*  Pwo0  = (float*) (ws + 24 * MB);  // 24-40  Wo partial z=0 (over qk)
    float*  Pwo1  = (float*) (ws + 40 * MB);  // 40-56  Wo partial z=1 (over Vt+hb)
    bf16_t* attnO = (bf16_t*)(ws + 56 * MB);  // 56-64  dead after Wo-proj
    bf16_t* mb    = (bf16_t*)(ws + 56 * MB);  // 56-64  written by ln_fuse
    bf16_t* ff1   = (bf16_t*)(ws + 24 * MB);  // 24-56  over Pwo (dead after ln_fuse)
    bf16_t* W1T   = (bf16_t*)(ws + 64 * MB);  // 64-72  dead after FF1
    float*  Pff1  = (float*) (ws + 56 * MB);  // 56-72  FF2 partial z=1 (over mb+W1T)
    bf16_t* WqkvT = (bf16_t*)(ws + 72 * MB);  // 72-78  dead after QKV gemm
    bf16_t* WoT   = (bf16_t*)(ws + 78 * MB);  // 78-80  dead after Wo-proj

    dim3 tt(16, 16);
    transpose_qkvo_kernel<<<dim3(16, 16, 4), tt, 0, stream>>>(Wq, Wk, Wv, Wo, WqkvT, WoT);
    transpose_bf16_kernel<<<dim3(64, 16), tt, 0, stream>>>(W1, W1T, D_, FF_);
    transpose_bf16_kernel<<<dim3(16, 64), tt, 0, stream>>>(W2, W2T, FF_, D_);

    ln_kernel<<<M_TOT, 256, 0, stream>>>(x, pos, g1, be1, hb);

    gemm_kernel<4, bf16_t><<<dim3(32, 24), 256, 0, stream>>>(hb, WqkvT, qk, nullptr,
                                                             Vt, M_TOT, 3072, D_);

    attn_kernel<<<dim3(16, 32), 256, 0, stream>>>(qk, Vt, attnO);

    // Wo projection: partials, no atomics
    gemm_splitk_st_kernel<<<dim3(32, 8, 2), 256, 0, stream>>>(attnO, WoT, Pwo0, Pwo1,
                                                              D_, D_, D_ / 2);

    // x2 = x + bo + Pwo0 + Pwo1 ; mb = LN(x2)
    ln_fuse_kernel<<<M_TOT, 256, 0, stream>>>(x, bo, Pwo0, Pwo1, g2, be2, x2, mb);

    // FF1: 256^2-tile 2-phase GEMM (16x16 grid = 256 blocks)
    gemm256_gelu_kernel<<<dim3(16, 16), 512, 0, stream>>>(mb, W1T, ff1, b1m, FF_, D_);

    // FF2: partial z=0 straight into d_out, z=1 into workspace
    gemm_splitk_st_kernel<<<dim3(32, 8, 2), 256, 0, stream>>>(ff1, W2T, (float*)d_out,
                                                              Pff1, D_, FF_, FF_ / 2);

    // d_out = x2 + b2m + P0(d_out) + Pff1
    reduce_out_kernel<<<M_TOT * D_ / 1024, 256, 0, stream>>>(x2, b2m, Pff1, (float*)d_out);

    (void)in_sizes; (void)n_in; (void)out_size; (void)ws_size;
}